// Round 4
// baseline (529.176 us; speedup 1.0000x reference)
//
#include <hip/hip_runtime.h>

// LSTM: T=512, B=4096, IN=1, H=12.
// R4: latency-bound → interleave C=4 independent cells per lane (20 cells
// per wave, 205 single-wave blocks). The 4 serial chains (gate FMAs →
// sigmoid/tanh transcendentals → ds_bpermute h-exchange) are independent
// and hide each other's latency; recurrent weights are shared across a
// lane's cells (they depend only on j). h exchange stays ds_bpermute
// (0 bank conflicts in R3). X staged to LDS per 64 steps; the 4 per-step
// x-values come from one ds_read_b128.

#define TT    512
#define NB    4096
#define HH    12
#define SLOTS 5            // lane groups of 12 (60/64 lanes active)
#define CPL   4            // cells per lane (ILP for latency hiding)
#define CPW   (SLOTS*CPL)  // 20 cells per wave
#define CHUNK 64           // X staging chunk; TT % CHUNK == 0

typedef float v2f __attribute__((ext_vector_type(2)));

static __device__ __forceinline__ v2f pkfma(v2f a, v2f b, v2f c) {
#if __has_builtin(__builtin_elementwise_fma)
    return __builtin_elementwise_fma(a, b, c);
#else
    v2f r; r.x = fmaf(a.x, b.x, c.x); r.y = fmaf(a.y, b.y, c.y); return r;
#endif
}

__device__ __forceinline__ float sigm(float x) {
    return __builtin_amdgcn_rcpf(1.0f + __builtin_amdgcn_exp2f(-1.4426950408889634f * x));
}
__device__ __forceinline__ float tanh_fast(float x) {
    return 1.0f - 2.0f * __builtin_amdgcn_rcpf(1.0f + __builtin_amdgcn_exp2f(2.8853900817779268f * x));
}

__global__ __launch_bounds__(64)
void lstm_fused(const float* __restrict__ X,
                const float* __restrict__ W_ih,
                const float* __restrict__ W_hh,
                const float* __restrict__ b_ih,
                const float* __restrict__ b_hh,
                const float* __restrict__ fc_w,
                const float* __restrict__ fc_b,
                float* __restrict__ out)
{
    __shared__ float xchunk[CHUNK][CPW];   // [row][slot], slot = cs*CPL + c

    const int lane = threadIdx.x;             // 0..63
    const int c0   = lane / HH;               // 0..4 valid, 5 for idle lanes
    const int j    = lane - c0 * HH;          // 0..11
    const int cs   = (c0 > SLOTS - 1) ? 0 : c0;
    const int cellbase = blockIdx.x * CPW;
    const bool writer  = (lane < SLOTS * HH);
    // cell of (cs, c): cellbase + cs*CPL + c
    int   cellc[CPL];
    bool  outlane[CPL];
    #pragma unroll
    for (int c = 0; c < CPL; ++c) {
        cellc[c]   = cellbase + cs * CPL + c;
        outlane[c] = writer && (j == 0) && (cellc[c] < NB);
    }

    // bpermute base byte address: lanes of my cell slot are cs*12 .. cs*12+11
    const int pbase = cs * HH * 4;

    // shared-per-lane weights: depend only on j
    v2f wif[HH], wgo[HH];
    float fcw[HH];
    #pragma unroll
    for (int k = 0; k < HH; ++k) {
        wif[k].x = W_hh[(0 * HH + j) * HH + k];
        wif[k].y = W_hh[(1 * HH + j) * HH + k];
        wgo[k].x = W_hh[(2 * HH + j) * HH + k];
        wgo[k].y = W_hh[(3 * HH + j) * HH + k];
        fcw[k] = fc_w[k];
    }
    v2f bif, bgo, wxif, wxgo;
    bif.x  = b_ih[0 * HH + j] + b_hh[0 * HH + j];
    bif.y  = b_ih[1 * HH + j] + b_hh[1 * HH + j];
    bgo.x  = b_ih[2 * HH + j] + b_hh[2 * HH + j];
    bgo.y  = b_ih[3 * HH + j] + b_hh[3 * HH + j];
    wxif.x = W_ih[0 * HH + j];   // IN == 1, W_ih flat [48]
    wxif.y = W_ih[1 * HH + j];
    wxgo.x = W_ih[2 * HH + j];
    wxgo.y = W_ih[3 * HH + j];
    const float fcb = fc_b[0];

    float cst[CPL];
    float hv[CPL][HH];
    #pragma unroll
    for (int c = 0; c < CPL; ++c) {
        cst[c] = 0.0f;
        #pragma unroll
        for (int k = 0; k < HH; ++k) hv[c][k] = 0.0f;
    }

    for (int t = 0; t < TT; ++t) {
        // stage X[t .. t+CHUNK) x [cellbase .. cellbase+CPW) into LDS
        if ((t & (CHUNK - 1)) == 0) {
            const int row = t + lane;          // CHUNK == 64 == wave size
            const float* src = X + (size_t)row * NB + cellbase;
            if (cellbase + CPW <= NB) {        // fast path: 5x float4
                float4 q0 = *(const float4*)(src + 0);
                float4 q1 = *(const float4*)(src + 4);
                float4 q2 = *(const float4*)(src + 8);
                float4 q3 = *(const float4*)(src + 12);
                float4 q4 = *(const float4*)(src + 16);
                *(float4*)&xchunk[lane][0]  = q0;
                *(float4*)&xchunk[lane][4]  = q1;
                *(float4*)&xchunk[lane][8]  = q2;
                *(float4*)&xchunk[lane][12] = q3;
                *(float4*)&xchunk[lane][16] = q4;
            } else {                           // ragged last block
                #pragma unroll
                for (int s = 0; s < CPW; ++s)
                    xchunk[lane][s] = (cellbase + s < NB) ? src[s] : 0.0f;
            }
        }

        // x values for my 4 cells: one b128 read (slot base cs*CPL, 16B aligned)
        const float4 xq = *(const float4*)&xchunk[t & (CHUNK - 1)][cs * CPL];
        const float xv[CPL] = {xq.x, xq.y, xq.z, xq.w};

        // 4 independent gate/activation chains
        int hb[CPL];
        #pragma unroll
        for (int c = 0; c < CPL; ++c) {
            v2f xvv; xvv.x = xv[c]; xvv.y = xv[c];
            v2f gif = pkfma(xvv, wxif, bif);
            v2f ggo = pkfma(xvv, wxgo, bgo);
            #pragma unroll
            for (int k = 0; k < HH; ++k) {
                v2f hk; hk.x = hv[c][k]; hk.y = hv[c][k];
                gif = pkfma(wif[k], hk, gif);
                ggo = pkfma(wgo[k], hk, ggo);
            }
            const float si = sigm(gif.x);
            const float sf = sigm(gif.y);
            const float tg = tanh_fast(ggo.x);
            const float so = sigm(ggo.y);
            cst[c] = fmaf(sf, cst[c], si * tg);
            hb[c] = __float_as_int(so * tanh_fast(cst[c]));
        }

        // exchange h_t cross-lane per cell (48 pipelined bpermutes)
        #pragma unroll
        for (int c = 0; c < CPL; ++c) {
            #pragma unroll
            for (int k = 0; k < HH; ++k)
                hv[c][k] = __int_as_float(
                    __builtin_amdgcn_ds_bpermute(pbase + 4 * k, hb[c]));
        }

        // fc output for step t (hv now holds h_t)
        #pragma unroll
        for (int c = 0; c < CPL; ++c) {
            if (outlane[c]) {
                float acc = fcb;
                #pragma unroll
                for (int k = 0; k < HH; ++k) acc = fmaf(hv[c][k], fcw[k], acc);
                out[(size_t)t * NB + cellc[c]] = acc;
            }
        }
    }
}

extern "C" void kernel_launch(void* const* d_in, const int* in_sizes, int n_in,
                              void* d_out, int out_size, void* d_ws, size_t ws_size,
                              hipStream_t stream) {
    const float* X    = (const float*)d_in[0];
    const float* W_ih = (const float*)d_in[1];
    const float* W_hh = (const float*)d_in[2];
    const float* b_ih = (const float*)d_in[3];
    const float* b_hh = (const float*)d_in[4];
    const float* fc_w = (const float*)d_in[5];
    const float* fc_b = (const float*)d_in[6];
    float* out = (float*)d_out;

    const int grid = (NB + CPW - 1) / CPW;   // 205 blocks of 1 wave
    lstm_fused<<<grid, 64, 0, stream>>>(X, W_ih, W_hh, b_ih, b_hh, fc_w, fc_b, out);
}

// Round 5
// 241.486 us; speedup vs baseline: 2.1913x; 2.1913x over previous
//
#include <hip/hip_runtime.h>

// LSTM: T=512, B=4096, IN=1, H=12.
// R5: chain-shortening. Total time == 512 x per-step serial chain (hop +
// gate-consume + activation tail); issue is NOT the bottleneck (R3/R4
// evidence), so: (1) gate weights/biases pre-scaled by -log2e (sigmoid) /
// +2log2e (tanh-g) so activations are rcp(1+exp2(g)) with no leading mul;
// (2) h = fma(-2*so, rc, so) with -2*so off-chain; (3) gate-consume chains
// split 2-way (depth 13 -> 7); (4) __launch_bounds__(64,1) to prevent the
// R4 spill disaster; (5) fc-out post-hop, off-chain. Structure otherwise
// R3: 5 cells/wave, 1 thread per (cell,j), ds_bpermute h-exchange,
// single-wave barrier-free blocks, X staged to LDS per 64 steps.

#define TT    512
#define NB    4096
#define HH    12
#define CPB   5      // cells per block (one wave, 60 active lanes)
#define CHUNK 64     // X staging chunk; TT % CHUNK == 0

typedef float v2f __attribute__((ext_vector_type(2)));

static __device__ __forceinline__ v2f pkfma(v2f a, v2f b, v2f c) {
#if __has_builtin(__builtin_elementwise_fma)
    return __builtin_elementwise_fma(a, b, c);
#else
    v2f r; r.x = fmaf(a.x, b.x, c.x); r.y = fmaf(a.y, b.y, c.y); return r;
#endif
}

#define SNEG (-1.44269504088896340736f)   // sigmoid pre-scale: -log2(e)
#define SPOS ( 2.88539008177792681472f)   // tanh pre-scale: +2*log2(e)

__global__ __launch_bounds__(64, 1)
void lstm_fused(const float* __restrict__ X,
                const float* __restrict__ W_ih,
                const float* __restrict__ W_hh,
                const float* __restrict__ b_ih,
                const float* __restrict__ b_hh,
                const float* __restrict__ fc_w,
                const float* __restrict__ fc_b,
                float* __restrict__ out)
{
    __shared__ float xchunk[CHUNK][CPB];

    const int lane = threadIdx.x;            // 0..63
    const int c0   = lane / HH;              // 0..4 valid, 5 for idle lanes
    const int j    = lane - c0 * HH;         // 0..11
    const int cs   = (c0 > CPB - 1) ? 0 : c0;   // clamped cell slot
    const int cellbase = blockIdx.x * CPB;
    const int cell = cellbase + cs;
    const bool active  = (lane < CPB * HH) && (cell < NB);
    const bool outlane = active && (j == 0);

    // bpermute source base byte address (lanes cs*12 .. cs*12+11)
    const int pbase = cs * HH * 4;

    // pre-scaled packed recurrent weights:
    //   wif[k] = (SNEG*W_i[j][k], SNEG*W_f[j][k])
    //   wgo[k] = (SPOS*W_g[j][k], SNEG*W_o[j][k])
    v2f wif[HH], wgo[HH];
    float fcw[HH];
    #pragma unroll
    for (int k = 0; k < HH; ++k) {
        wif[k].x = SNEG * W_hh[(0 * HH + j) * HH + k];
        wif[k].y = SNEG * W_hh[(1 * HH + j) * HH + k];
        wgo[k].x = SPOS * W_hh[(2 * HH + j) * HH + k];
        wgo[k].y = SNEG * W_hh[(3 * HH + j) * HH + k];
        fcw[k] = fc_w[k];
    }
    v2f bif, bgo, wxif, wxgo;
    bif.x  = SNEG * (b_ih[0 * HH + j] + b_hh[0 * HH + j]);
    bif.y  = SNEG * (b_ih[1 * HH + j] + b_hh[1 * HH + j]);
    bgo.x  = SPOS * (b_ih[2 * HH + j] + b_hh[2 * HH + j]);
    bgo.y  = SNEG * (b_ih[3 * HH + j] + b_hh[3 * HH + j]);
    wxif.x = SNEG * W_ih[0 * HH + j];   // IN == 1, W_ih flat [48]
    wxif.y = SNEG * W_ih[1 * HH + j];
    wxgo.x = SPOS * W_ih[2 * HH + j];
    wxgo.y = SNEG * W_ih[3 * HH + j];
    const float fcb = fc_b[0];

    float cst = 0.0f;     // cell state c[cell][j]
    float hv[HH];         // gathered h of my cell; starts at h0 = 0
    #pragma unroll
    for (int k = 0; k < HH; ++k) hv[k] = 0.0f;

    for (int t = 0; t < TT; ++t) {
        // stage X[t .. t+CHUNK) for this block's cells into LDS
        if ((t & (CHUNK - 1)) == 0) {
            const int tt = t + lane;   // CHUNK == 64 == wave size
            #pragma unroll
            for (int k = 0; k < CPB; ++k) {
                const int cc = cellbase + k;
                xchunk[lane][k] = (cc < NB) ? X[tt * NB + cc] : 0.0f;
            }
        }

        const float xv = xchunk[t & (CHUNK - 1)][cs];
        v2f xvv; xvv.x = xv; xvv.y = xv;

        // gate accumulation: 2-way split chains (depth 7 instead of 13)
        v2f giA = pkfma(xvv, wxif, bif);
        v2f goA = pkfma(xvv, wxgo, bgo);
        v2f giB; giB.x = 0.0f; giB.y = 0.0f;
        v2f goB; goB.x = 0.0f; goB.y = 0.0f;
        #pragma unroll
        for (int k = 0; k < 6; ++k) {
            v2f hka; hka.x = hv[k];     hka.y = hv[k];
            v2f hkb; hkb.x = hv[k + 6]; hkb.y = hv[k + 6];
            giA = pkfma(wif[k], hka, giA);
            goA = pkfma(wgo[k], hka, goA);
            giB = pkfma(wif[k + 6], hkb, giB);
            goB = pkfma(wgo[k + 6], hkb, goB);
        }
        const v2f gif = giA + giB;   // v_pk_add_f32
        const v2f ggo = goA + goB;

        // activations (weights pre-scaled: no leading mul)
        const float si = __builtin_amdgcn_rcpf(1.0f + __builtin_amdgcn_exp2f(gif.x));
        const float sf = __builtin_amdgcn_rcpf(1.0f + __builtin_amdgcn_exp2f(gif.y));
        const float rg = __builtin_amdgcn_rcpf(1.0f + __builtin_amdgcn_exp2f(ggo.x));
        const float so = __builtin_amdgcn_rcpf(1.0f + __builtin_amdgcn_exp2f(ggo.y));
        const float tg = fmaf(-2.0f, rg, 1.0f);
        cst = fmaf(sf, cst, si * tg);
        // h = so * tanh(cst) = fma(-2*so, rc, so); -2*so runs parallel to rc
        const float rc   = __builtin_amdgcn_rcpf(1.0f + __builtin_amdgcn_exp2f(SPOS * cst));
        const float m2so = -2.0f * so;
        const float hn   = fmaf(m2so, rc, so);

        // exchange h_t cross-lane (12 pipelined bpermutes, consumed in order)
        const int hbits = __float_as_int(hn);
        #pragma unroll
        for (int k = 0; k < HH; ++k)
            hv[k] = __int_as_float(__builtin_amdgcn_ds_bpermute(pbase + 4 * k, hbits));

        // fc output for step t (hv now holds h_t); off the critical chain
        if (outlane) {
            float acc = fcb;
            #pragma unroll
            for (int k = 0; k < HH; ++k) acc = fmaf(hv[k], fcw[k], acc);
            out[(size_t)t * NB + cell] = acc;
        }
    }
}

extern "C" void kernel_launch(void* const* d_in, const int* in_sizes, int n_in,
                              void* d_out, int out_size, void* d_ws, size_t ws_size,
                              hipStream_t stream) {
    const float* X    = (const float*)d_in[0];
    const float* W_ih = (const float*)d_in[1];
    const float* W_hh = (const float*)d_in[2];
    const float* b_ih = (const float*)d_in[3];
    const float* b_hh = (const float*)d_in[4];
    const float* fc_w = (const float*)d_in[5];
    const float* fc_b = (const float*)d_in[6];
    float* out = (float*)d_out;

    const int grid = (NB + CPB - 1) / CPB;   // 820 blocks of 1 wave
    lstm_fused<<<grid, 64, 0, stream>>>(X, W_ih, W_hh, b_ih, b_hh, fc_w, fc_b, out);
}

// Round 6
// 204.902 us; speedup vs baseline: 2.5826x; 1.1785x over previous
//
#include <hip/hip_runtime.h>

// LSTM: T=512, B=4096, IN=1, H=12.
// R6: DS-free h-exchange. One cell per 16-lane DPP row (j = lane&15; lanes
// 12..15 are finite "clone" lanes), 4 cells/wave, 1024 waves -> all 1024
// SIMDs busy. h exchanged with 15 v_mov_b32 dpp row_ror:r (VALU latency,
// ~4-8 cyc) instead of ds_bpermute (~120+ cyc + lgkm waits) — R5 evidence:
// step period 610 cyc vs 170 cyc issue, gap = DS round-trips on the chain.
// DPP ror direction is probed at setup (ror the lane-id), and weights are
// stored per-source-slot (wifU/wgoU/fcwU[r] = weight for the h value that
// ror r delivers), zero-gated for clone-lane sources. fc dot rides the same
// rors (lagged one step). xv ds_read issued early, consumed last (x-proj
// folded in after the ror block) to stay off the serial chain. Weights
// pre-scaled (sigmoid: -log2e, tanh: +2log2e) per R5. launch_bounds(64,1)
// so nothing spills (R4 lesson).

#define TT    512
#define NB    4096
#define HH    12
#define RPW   4      // rows (cells) per wave
#define CHUNK 64     // X staging chunk; TT % CHUNK == 0

typedef float v2f __attribute__((ext_vector_type(2)));

static __device__ __forceinline__ v2f pkfma(v2f a, v2f b, v2f c) {
#if __has_builtin(__builtin_elementwise_fma)
    return __builtin_elementwise_fma(a, b, c);
#else
    v2f r; r.x = fmaf(a.x, b.x, c.x); r.y = fmaf(a.y, b.y, c.y); return r;
#endif
}

#define SNEG (-1.44269504088896340736f)   // sigmoid pre-scale: -log2(e)
#define SPOS ( 2.88539008177792681472f)   // tanh pre-scale: +2*log2(e)

#define ROR(r) (0x120 + (r))              // DPP ctrl: row_ror:r

__global__ __launch_bounds__(64, 1)
void lstm_fused(const float* __restrict__ X,
                const float* __restrict__ W_ih,
                const float* __restrict__ W_hh,
                const float* __restrict__ b_ih,
                const float* __restrict__ b_hh,
                const float* __restrict__ fc_w,
                const float* __restrict__ fc_b,
                float* __restrict__ out)
{
    __shared__ float xchunk[CHUNK][RPW];

    const int lane = threadIdx.x;        // 0..63
    const int row  = lane >> 4;          // 0..3  : cell slot
    const int j    = lane & 15;          // 0..11 real, 12..15 clone lanes
    const int cellbase = blockIdx.x * RPW;
    const int cell = cellbase + row;     // grid sized so cell < NB always

    // ---- probe DPP ror direction: sid[r] = within-row source lane of ror r
    int sid[16];
    sid[0] = j;
#define PROBE(r) sid[r] = __builtin_amdgcn_update_dpp(0, j, ROR(r), 0xF, 0xF, true);
    PROBE(1)  PROBE(2)  PROBE(3)  PROBE(4)  PROBE(5)
    PROBE(6)  PROBE(7)  PROBE(8)  PROBE(9)  PROBE(10)
    PROBE(11) PROBE(12) PROBE(13) PROBE(14) PROBE(15)
#undef PROBE

    // ---- per-source-slot weight tables (r=0 is the local contribution)
    const int jc = (j < HH) ? j : (HH - 1);   // clamp clone lanes (OOB + finite)
    v2f   wifU[16], wgoU[16];
    float fcwU[16];
    #pragma unroll
    for (int r = 0; r < 16; ++r) {
        const int  s  = sid[r];
        const int  sc = (s < HH) ? s : (HH - 1);
        // active lanes must zero-weight clone sources; clone lanes just need
        // finite values (their outputs are consumed with zero weight anyway)
        const float g = ((j >= HH) || (s < HH)) ? 1.0f : 0.0f;
        wifU[r].x = g * SNEG * W_hh[(0 * HH + jc) * HH + sc];
        wifU[r].y = g * SNEG * W_hh[(1 * HH + jc) * HH + sc];
        wgoU[r].x = g * SPOS * W_hh[(2 * HH + jc) * HH + sc];
        wgoU[r].y = g * SNEG * W_hh[(3 * HH + jc) * HH + sc];
        fcwU[r]   = g * fc_w[sc];
    }
    v2f bif, bgo, wxif, wxgo;
    bif.x  = SNEG * (b_ih[0 * HH + jc] + b_hh[0 * HH + jc]);
    bif.y  = SNEG * (b_ih[1 * HH + jc] + b_hh[1 * HH + jc]);
    bgo.x  = SPOS * (b_ih[2 * HH + jc] + b_hh[2 * HH + jc]);
    bgo.y  = SNEG * (b_ih[3 * HH + jc] + b_hh[3 * HH + jc]);
    wxif.x = SNEG * W_ih[0 * HH + jc];   // IN == 1, W_ih flat [48]
    wxif.y = SNEG * W_ih[1 * HH + jc];
    wxgo.x = SPOS * W_ih[2 * HH + jc];
    wxgo.y = SNEG * W_ih[3 * HH + jc];
    const float fcb = fc_b[0];

    float cst = 0.0f;    // my cell-state element c[cell][j]
    float hn  = 0.0f;    // my h element h[cell][j]  (h0 = 0)
    int hbits = 0;

    for (int t = 0; t < TT; ++t) {
        // stage X[t..t+64) x [cellbase..cellbase+4) : one float4 per lane
        if ((t & (CHUNK - 1)) == 0) {
            const float4 q = *(const float4*)(X + (size_t)(t + lane) * NB + cellbase);
            *(float4*)&xchunk[lane][0] = q;
        }
        // issue the xv read early; it is consumed LAST (x-proj after rors)
        const float xv = xchunk[t & (CHUNK - 1)][row];

        // gate accumulation over h_{t-1}: local + 15 DPP rors, 2-way split
        v2f gifA = bif, goA = bgo;
        v2f gifB; gifB.x = 0.0f; gifB.y = 0.0f;
        v2f goB;  goB.x  = 0.0f; goB.y  = 0.0f;
        float fco = fcb;
        {   // local contribution (r = 0)
            v2f hk; hk.x = hn; hk.y = hn;
            gifA = pkfma(wifU[0], hk, gifA);
            goA  = pkfma(wgoU[0], hk, goA);
            fco  = fmaf(hn, fcwU[0], fco);
        }
#define XR(r) { \
        const int   hr_##r = __builtin_amdgcn_update_dpp(0, hbits, ROR(r), 0xF, 0xF, true); \
        const float hf = __int_as_float(hr_##r); \
        v2f hk; hk.x = hf; hk.y = hf; \
        if ((r) < 8) { gifA = pkfma(wifU[r], hk, gifA); goA = pkfma(wgoU[r], hk, goA); } \
        else         { gifB = pkfma(wifU[r], hk, gifB); goB = pkfma(wgoU[r], hk, goB); } \
        fco = fmaf(hf, fcwU[r], fco); }
        XR(1)  XR(2)  XR(3)  XR(4)  XR(5)
        XR(6)  XR(7)  XR(8)  XR(9)  XR(10)
        XR(11) XR(12) XR(13) XR(14) XR(15)

        // fc output for step t-1 (exchange above delivered h_{t-1})
        if (t > 0 && j == 0) out[(size_t)(t - 1) * NB + cell] = fco;

        v2f gif = gifA + gifB;     // v_pk_add_f32
        v2f ggo = goA + goB;
        v2f xvv; xvv.x = xv; xvv.y = xv;
        gif = pkfma(xvv, wxif, gif);   // x-projection last: hides the ds_read
        ggo = pkfma(xvv, wxgo, ggo);

        // activations (weights pre-scaled: rcp(1+exp2(g)) directly)
        const float si = __builtin_amdgcn_rcpf(1.0f + __builtin_amdgcn_exp2f(gif.x));
        const float sf = __builtin_amdgcn_rcpf(1.0f + __builtin_amdgcn_exp2f(gif.y));
        const float rg = __builtin_amdgcn_rcpf(1.0f + __builtin_amdgcn_exp2f(ggo.x));
        const float so = __builtin_amdgcn_rcpf(1.0f + __builtin_amdgcn_exp2f(ggo.y));
        const float tg = fmaf(-2.0f, rg, 1.0f);
        cst = fmaf(sf, cst, si * tg);
        const float rc   = __builtin_amdgcn_rcpf(1.0f + __builtin_amdgcn_exp2f(SPOS * cst));
        const float m2so = -2.0f * so;
        hn    = fmaf(m2so, rc, so);
        hbits = __float_as_int(hn);
    }

    // final fc output for t = TT-1: one more exchange, fc-only
    {
        float fco = fmaf(hn, fcwU[0], fcb);
#define XF(r) { \
        const int hr_##r = __builtin_amdgcn_update_dpp(0, hbits, ROR(r), 0xF, 0xF, true); \
        fco = fmaf(__int_as_float(hr_##r), fcwU[r], fco); }
        XF(1)  XF(2)  XF(3)  XF(4)  XF(5)
        XF(6)  XF(7)  XF(8)  XF(9)  XF(10)
        XF(11) XF(12) XF(13) XF(14) XF(15)
        if (j == 0) out[(size_t)(TT - 1) * NB + cell] = fco;
    }
}

extern "C" void kernel_launch(void* const* d_in, const int* in_sizes, int n_in,
                              void* d_out, int out_size, void* d_ws, size_t ws_size,
                              hipStream_t stream) {
    const float* X    = (const float*)d_in[0];
    const float* W_ih = (const float*)d_in[1];
    const float* W_hh = (const float*)d_in[2];
    const float* b_ih = (const float*)d_in[3];
    const float* b_hh = (const float*)d_in[4];
    const float* fc_w = (const float*)d_in[5];
    const float* fc_b = (const float*)d_in[6];
    float* out = (float*)d_out;

    const int grid = NB / RPW;   // 1024 single-wave blocks: every SIMD busy
    lstm_fused<<<grid, 64, 0, stream>>>(X, W_ih, W_hh, b_ih, b_hh, fc_w, fc_b, out);
}

// Round 7
// 184.045 us; speedup vs baseline: 2.8753x; 1.1133x over previous
//
#include <hip/hip_runtime.h>

// LSTM: T=512, B=4096, IN=1, H=12.
// R7 (on R6's DPP structure): issue/stall trim.
//  - fc dot: ring all-reduce (mul + 4x ror-add) instead of 16 fmas riding
//    the gate rors; kills the fcwU table and the lagged-output epilogue.
//  - xv: transposed LDS chunk [row][time] -> one ds_read_b128 per 4 steps,
//    issued ~100 issue-cycles before first use (x-proj is last) so the DS
//    latency is buried.
//  - X staging: next chunk's global_load issued one chunk (64 steps) early
//    into registers; ds_writes at the boundary find vmcnt already satisfied.
// Layout: one cell per 16-lane DPP row (j = lane&15, lanes 12..15 clones),
// 4 cells/wave, 1024 single-wave blocks = every SIMD busy. h exchanged with
// 15 v_mov_b32 dpp row_ror (probed direction, per-source weight tables,
// zero-gated clones). Weights pre-scaled (sigmoid -log2e, tanh +2log2e).

#define TT    512
#define NB    4096
#define HH    12
#define RPW   4      // rows (cells) per wave
#define CHUNK 64     // X staging chunk; TT % CHUNK == 0

typedef float v2f __attribute__((ext_vector_type(2)));

static __device__ __forceinline__ v2f pkfma(v2f a, v2f b, v2f c) {
#if __has_builtin(__builtin_elementwise_fma)
    return __builtin_elementwise_fma(a, b, c);
#else
    v2f r; r.x = fmaf(a.x, b.x, c.x); r.y = fmaf(a.y, b.y, c.y); return r;
#endif
}

#define SNEG (-1.44269504088896340736f)   // sigmoid pre-scale: -log2(e)
#define SPOS ( 2.88539008177792681472f)   // tanh pre-scale: +2*log2(e)

#define ROR(r) (0x120 + (r))              // DPP ctrl: row_ror:r

__global__ __launch_bounds__(64, 1)
void lstm_fused(const float* __restrict__ X,
                const float* __restrict__ W_ih,
                const float* __restrict__ W_hh,
                const float* __restrict__ b_ih,
                const float* __restrict__ b_hh,
                const float* __restrict__ fc_w,
                const float* __restrict__ fc_b,
                float* __restrict__ out)
{
    __shared__ float xchunk[RPW][CHUNK];   // transposed: [cell row][time]

    const int lane = threadIdx.x;        // 0..63
    const int row  = lane >> 4;          // 0..3  : cell slot
    const int j    = lane & 15;          // 0..11 real, 12..15 clone lanes
    const int cellbase = blockIdx.x * RPW;
    const int cell = cellbase + row;     // grid sized so cell < NB always

    // ---- probe DPP ror direction: sid[r] = within-row source lane of ror r
    int sid[16];
    sid[0] = j;
#define PROBE(r) sid[r] = __builtin_amdgcn_update_dpp(0, j, ROR(r), 0xF, 0xF, true);
    PROBE(1)  PROBE(2)  PROBE(3)  PROBE(4)  PROBE(5)
    PROBE(6)  PROBE(7)  PROBE(8)  PROBE(9)  PROBE(10)
    PROBE(11) PROBE(12) PROBE(13) PROBE(14) PROBE(15)
#undef PROBE

    // ---- per-source-slot gate weight tables (r=0 is local contribution)
    const int jc = (j < HH) ? j : (HH - 1);   // clamp clone lanes (finite)
    v2f wifU[16], wgoU[16];
    #pragma unroll
    for (int r = 0; r < 16; ++r) {
        const int  s  = sid[r];
        const int  sc = (s < HH) ? s : (HH - 1);
        const float g = ((j >= HH) || (s < HH)) ? 1.0f : 0.0f;
        wifU[r].x = g * SNEG * W_hh[(0 * HH + jc) * HH + sc];
        wifU[r].y = g * SNEG * W_hh[(1 * HH + jc) * HH + sc];
        wgoU[r].x = g * SPOS * W_hh[(2 * HH + jc) * HH + sc];
        wgoU[r].y = g * SNEG * W_hh[(3 * HH + jc) * HH + sc];
    }
    v2f bif, bgo, wxif, wxgo;
    bif.x  = SNEG * (b_ih[0 * HH + jc] + b_hh[0 * HH + jc]);
    bif.y  = SNEG * (b_ih[1 * HH + jc] + b_hh[1 * HH + jc]);
    bgo.x  = SPOS * (b_ih[2 * HH + jc] + b_hh[2 * HH + jc]);
    bgo.y  = SNEG * (b_ih[3 * HH + jc] + b_hh[3 * HH + jc]);
    wxif.x = SNEG * W_ih[0 * HH + jc];   // IN == 1, W_ih flat [48]
    wxif.y = SNEG * W_ih[1 * HH + jc];
    wxgo.x = SPOS * W_ih[2 * HH + jc];
    wxgo.y = SNEG * W_ih[3 * HH + jc];
    const float fcb  = fc_b[0];
    const float fcwj = (j < HH) ? fc_w[j] : 0.0f;   // clones contribute 0

    float cst = 0.0f;    // my cell-state element c[cell][j]
    float hn  = 0.0f;    // my h element h[cell][j]  (h0 = 0)
    int hbits = 0;

    // prefetch chunk 0 of X into registers
    float4 gq = *(const float4*)(X + (size_t)lane * NB + cellbase);

    for (int tc = 0; tc < TT; tc += CHUNK) {
        // stage prefetched chunk to LDS (transposed), prefetch next chunk
        xchunk[0][lane] = gq.x;
        xchunk[1][lane] = gq.y;
        xchunk[2][lane] = gq.z;
        xchunk[3][lane] = gq.w;
        if (tc + CHUNK < TT)
            gq = *(const float4*)(X + (size_t)(tc + CHUNK + lane) * NB + cellbase);

        for (int t4 = 0; t4 < CHUNK; t4 += 4) {
            // 4 steps' worth of x for my row: one broadcast ds_read_b128,
            // consumed only at each step's x-projection (last) -> latency buried
            const float4 xq = *(const float4*)&xchunk[row][t4];
            const float xs[4] = {xq.x, xq.y, xq.z, xq.w};

            #pragma unroll
            for (int u = 0; u < 4; ++u) {
                // gather h_{t-1} + gate accumulation: local + 15 DPP rors
                v2f gifA = bif, goA = bgo;
                v2f gifB; gifB.x = 0.0f; gifB.y = 0.0f;
                v2f goB;  goB.x  = 0.0f; goB.y  = 0.0f;
                {   // local contribution (r = 0)
                    v2f hk; hk.x = hn; hk.y = hn;
                    gifA = pkfma(wifU[0], hk, gifA);
                    goA  = pkfma(wgoU[0], hk, goA);
                }
#define XR(r) { \
                const int hr_##r = __builtin_amdgcn_update_dpp(0, hbits, ROR(r), 0xF, 0xF, true); \
                const float hf = __int_as_float(hr_##r); \
                v2f hk; hk.x = hf; hk.y = hf; \
                if ((r) < 8) { gifA = pkfma(wifU[r], hk, gifA); goA = pkfma(wgoU[r], hk, goA); } \
                else         { gifB = pkfma(wifU[r], hk, gifB); goB = pkfma(wgoU[r], hk, goB); } }
                XR(1)  XR(2)  XR(3)  XR(4)  XR(5)
                XR(6)  XR(7)  XR(8)  XR(9)  XR(10)
                XR(11) XR(12) XR(13) XR(14) XR(15)
#undef XR
                v2f gif = gifA + gifB;     // v_pk_add_f32
                v2f ggo = goA + goB;
                v2f xvv; xvv.x = xs[u]; xvv.y = xs[u];
                gif = pkfma(xvv, wxif, gif);   // x-projection last
                ggo = pkfma(xvv, wxgo, ggo);

                // activations (pre-scaled: rcp(1+exp2(g)) directly)
                const float si = __builtin_amdgcn_rcpf(1.0f + __builtin_amdgcn_exp2f(gif.x));
                const float sf = __builtin_amdgcn_rcpf(1.0f + __builtin_amdgcn_exp2f(gif.y));
                const float rg = __builtin_amdgcn_rcpf(1.0f + __builtin_amdgcn_exp2f(ggo.x));
                const float so = __builtin_amdgcn_rcpf(1.0f + __builtin_amdgcn_exp2f(ggo.y));
                const float tg = fmaf(-2.0f, rg, 1.0f);
                cst = fmaf(sf, cst, si * tg);
                const float rc   = __builtin_amdgcn_rcpf(1.0f + __builtin_amdgcn_exp2f(SPOS * cst));
                const float m2so = -2.0f * so;
                hn    = fmaf(m2so, rc, so);
                hbits = __float_as_int(hn);

                // fc output for step t: ring all-reduce of hn*fcw over the row
                // (ror by 8,4,2,1 with add = full row sum in every lane;
                //  independent of next step's ror/gate chain -> overlaps it)
                float p = hn * fcwj;
                p += __int_as_float(__builtin_amdgcn_update_dpp(0, __float_as_int(p), ROR(8), 0xF, 0xF, true));
                p += __int_as_float(__builtin_amdgcn_update_dpp(0, __float_as_int(p), ROR(4), 0xF, 0xF, true));
                p += __int_as_float(__builtin_amdgcn_update_dpp(0, __float_as_int(p), ROR(2), 0xF, 0xF, true));
                p += __int_as_float(__builtin_amdgcn_update_dpp(0, __float_as_int(p), ROR(1), 0xF, 0xF, true));
                if (j == 0) out[(size_t)(tc + t4 + u) * NB + cell] = p + fcb;
            }
        }
    }
}

extern "C" void kernel_launch(void* const* d_in, const int* in_sizes, int n_in,
                              void* d_out, int out_size, void* d_ws, size_t ws_size,
                              hipStream_t stream) {
    const float* X    = (const float*)d_in[0];
    const float* W_ih = (const float*)d_in[1];
    const float* W_hh = (const float*)d_in[2];
    const float* b_ih = (const float*)d_in[3];
    const float* b_hh = (const float*)d_in[4];
    const float* fc_w = (const float*)d_in[5];
    const float* fc_b = (const float*)d_in[6];
    float* out = (float*)d_out;

    const int grid = NB / RPW;   // 1024 single-wave blocks: every SIMD busy
    lstm_fused<<<grid, 64, 0, stream>>>(X, W_ih, W_hh, b_ih, b_hh, fc_w, fc_b, out);
}